// Round 1
// baseline (212.033 us; speedup 1.0000x reference)
//
#include <hip/hip_runtime.h>
#include <hip/hip_bf16.h>
#include <type_traits>

// MHA: x[2,2048,1024] fp32; W*[1024,1024] fp32; out fp32.
// Pipeline: cvt->bf16, QKV gemm (bf16 mfma), V-transpose, flash attn, out gemm.

typedef __attribute__((ext_vector_type(4))) float f32x4;
typedef __attribute__((ext_vector_type(8))) short s16x8;

#define GLDS16(g, l)                                                       \
  __builtin_amdgcn_global_load_lds(                                        \
      (const __attribute__((address_space(1))) unsigned int*)(g),          \
      (__attribute__((address_space(3))) unsigned int*)(l), 16, 0, 0)

__device__ __forceinline__ unsigned short f2bf(float f) {
  unsigned int u = __builtin_bit_cast(unsigned int, f);
  u += 0x7fffu + ((u >> 16) & 1u);
  return (unsigned short)(u >> 16);
}

__global__ void cvt_f32_bf16(const float* __restrict__ in,
                             unsigned short* __restrict__ out, int n) {
  int i = (blockIdx.x * blockDim.x + threadIdx.x) * 4;
  if (i < n) {
    float4 v = *reinterpret_cast<const float4*>(in + i);
    ushort4 o;
    o.x = f2bf(v.x); o.y = f2bf(v.y); o.z = f2bf(v.z); o.w = f2bf(v.w);
    *reinterpret_cast<ushort4*>(out + i) = o;
  }
}

__global__ void concat3(const float* __restrict__ a, const float* __restrict__ b,
                        const float* __restrict__ c, float* __restrict__ out) {
  int i = blockIdx.x * blockDim.x + threadIdx.x;  // 3072 threads
  const float* src = (i < 1024) ? a : ((i < 2048) ? b : c);
  out[i] = src[i & 1023];
}

// C[M,N] = A[M,K] * B[N,K]^T + bias ; A,B bf16 (ushort), C f32 or bf16.
// 128x128 tile, BK=32, 4 waves (2x2), 16x16x32 bf16 MFMA, global_load_lds.
template <typename CT>
__global__ __launch_bounds__(256, 2) void gemm_bt(
    const unsigned short* __restrict__ A, const unsigned short* __restrict__ B,
    CT* __restrict__ C, int M, int N, int K, const float* __restrict__ bias) {
  __shared__ unsigned short As[128 * 32];
  __shared__ unsigned short Bs[128 * 32];
  const int tid = threadIdx.x;
  const int wv = tid >> 6, lane = tid & 63;
  const int g = lane >> 4, c16 = lane & 15;
  const int wm = wv >> 1, wn = wv & 1;
  const int bm = blockIdx.y, bn = blockIdx.x;

  const unsigned short* Ab = A + (size_t)bm * 128 * K;
  const unsigned short* Bb = B + (size_t)bn * 128 * K;

  f32x4 acc[4][4] = {};

  for (int k0 = 0; k0 < K; k0 += 32) {
    __syncthreads();
#pragma unroll
    for (int r = 0; r < 2; ++r) {
      int i = r * 256 + tid;
      int row = i >> 2, col = (i & 3) * 8;
      GLDS16(Ab + (size_t)row * K + k0 + col, &As[i * 8]);
    }
#pragma unroll
    for (int r = 0; r < 2; ++r) {
      int i = r * 256 + tid;
      int row = i >> 2, col = (i & 3) * 8;
      GLDS16(Bb + (size_t)row * K + k0 + col, &Bs[i * 8]);
    }
    __syncthreads();

    s16x8 af[4], bfv[4];
#pragma unroll
    for (int m = 0; m < 4; ++m)
      af[m] = *(const s16x8*)&As[(wm * 64 + m * 16 + c16) * 32 + g * 8];
#pragma unroll
    for (int n = 0; n < 4; ++n)
      bfv[n] = *(const s16x8*)&Bs[(wn * 64 + n * 16 + c16) * 32 + g * 8];
#pragma unroll
    for (int m = 0; m < 4; ++m)
#pragma unroll
      for (int n = 0; n < 4; ++n)
        acc[m][n] = __builtin_amdgcn_mfma_f32_16x16x32_bf16(af[m], bfv[n],
                                                            acc[m][n], 0, 0, 0);
  }

#pragma unroll
  for (int m = 0; m < 4; ++m) {
#pragma unroll
    for (int n = 0; n < 4; ++n) {
      int col = bn * 128 + wn * 64 + n * 16 + c16;
      float bb = bias ? bias[col] : 0.f;
#pragma unroll
      for (int j = 0; j < 4; ++j) {
        int row = bm * 128 + wm * 64 + m * 16 + g * 4 + j;
        float v = acc[m][n][j] + bb;
        if constexpr (std::is_same<CT, float>::value)
          C[(size_t)row * N + col] = v;
        else
          C[(size_t)row * N + col] = f2bf(v);
      }
    }
  }
}

// vt[bh][64][2048] = transpose of V part of qkv (cols 2048..3071) per (b,h).
__global__ void transpose_v(const unsigned short* __restrict__ qkv,
                            unsigned short* __restrict__ vt) {
  __shared__ unsigned short T[64 * 80];
  const int tid = threadIdx.x;
  const int st = blockIdx.x, bh = blockIdx.y;
  const int b = bh >> 4, h = bh & 15;
  const int s0 = st * 64;

  int srow = tid >> 2, d0 = (tid & 3) * 16;
  const unsigned short* src =
      qkv + (size_t)(b * 2048 + s0 + srow) * 3072 + 2048 + h * 64 + d0;
  s16x8 v0 = *(const s16x8*)(src);
  s16x8 v1 = *(const s16x8*)(src + 8);
  *(s16x8*)&T[srow * 80 + d0] = v0;
  *(s16x8*)&T[srow * 80 + d0 + 8] = v1;
  __syncthreads();

  int drow = tid >> 2, sl = (tid & 3) * 16;
  s16x8 o0, o1;
#pragma unroll
  for (int j = 0; j < 8; ++j) o0[j] = (short)T[(sl + j) * 80 + drow];
#pragma unroll
  for (int j = 0; j < 8; ++j) o1[j] = (short)T[(sl + 8 + j) * 80 + drow];
  unsigned short* dst = vt + (size_t)(bh * 64 + drow) * 2048 + s0 + sl;
  *(s16x8*)dst = o0;
  *(s16x8*)(dst + 8) = o1;
}

// Flash attention: grid (32 qtiles, 32 bh), 256 thr = 4 waves x 16 q-rows.
// KB=64 keys/iter. LDS tiles [.][64] bf16 XOR-swizzled (pre-swizzled global
// source for global_load_lds + swizzled reads) to avoid 128B-row conflicts.
__global__ __launch_bounds__(256, 2) void flash_attn(
    const unsigned short* __restrict__ qkv, const unsigned short* __restrict__ vt,
    unsigned short* __restrict__ attn) {
  __shared__ unsigned short Qs[64 * 64];
  __shared__ unsigned short Ks[64 * 64];
  __shared__ unsigned short VTs[64 * 64];
  __shared__ unsigned short Ps[4][16 * 64];

  const int tid = threadIdx.x;
  const int wv = tid >> 6, lane = tid & 63;
  const int g = lane >> 4, c16 = lane & 15;
  const int qt = blockIdx.x, bh = blockIdx.y;
  const int b = bh >> 4, h = bh & 15;
  const int q0 = qt * 64;

#pragma unroll
  for (int r = 0; r < 2; ++r) {
    int i = r * 256 + tid;
    int row = i >> 3, cs = i & 7;
    int qc = cs ^ (row & 7);
    GLDS16(qkv + (size_t)(b * 2048 + q0 + row) * 3072 + h * 64 + qc * 8,
           &Qs[i * 8]);
  }
  __syncthreads();

  s16x8 qf0, qf1;
  {
    int row = wv * 16 + c16;
    qf0 = *(const s16x8*)&Qs[row * 64 + ((g) ^ (row & 7)) * 8];
    qf1 = *(const s16x8*)&Qs[row * 64 + ((4 + g) ^ (row & 7)) * 8];
  }

  float m_run[4], l_run[4];
#pragma unroll
  for (int j = 0; j < 4; ++j) { m_run[j] = -__builtin_inff(); l_run[j] = 0.f; }
  f32x4 o[4] = {};

  const float SCL = 0.125f * 1.44269504088896340736f;  // (1/sqrt(64))*log2(e)

  for (int kt = 0; kt < 32; ++kt) {
    __syncthreads();
    const int k0 = kt * 64;
#pragma unroll
    for (int r = 0; r < 2; ++r) {
      int i = r * 256 + tid;
      int row = i >> 3, cs = i & 7;
      int qc = cs ^ (row & 7);
      GLDS16(qkv + (size_t)(b * 2048 + k0 + row) * 3072 + 1024 + h * 64 + qc * 8,
             &Ks[i * 8]);
    }
#pragma unroll
    for (int r = 0; r < 2; ++r) {
      int i = r * 256 + tid;
      int row = i >> 3, cs = i & 7;
      int qc = cs ^ (row & 7);
      GLDS16(vt + (size_t)(bh * 64 + row) * 2048 + k0 + qc * 8, &VTs[i * 8]);
    }
    __syncthreads();

    // QK^T: scores [16 q][64 k] per wave
    f32x4 sc[4];
#pragma unroll
    for (int tt = 0; tt < 4; ++tt) {
      int row = tt * 16 + c16;
      s16x8 kf0 = *(const s16x8*)&Ks[row * 64 + ((g) ^ (row & 7)) * 8];
      s16x8 kf1 = *(const s16x8*)&Ks[row * 64 + ((4 + g) ^ (row & 7)) * 8];
      f32x4 a = {};
      a = __builtin_amdgcn_mfma_f32_16x16x32_bf16(qf0, kf0, a, 0, 0, 0);
      a = __builtin_amdgcn_mfma_f32_16x16x32_bf16(qf1, kf1, a, 0, 0, 0);
      sc[tt] = a;
    }

    // online softmax (raw-score domain, exp2 with folded scale)
    float corr[4];
#pragma unroll
    for (int j = 0; j < 4; ++j) {
      float t = fmaxf(fmaxf(sc[0][j], sc[1][j]), fmaxf(sc[2][j], sc[3][j]));
#pragma unroll
      for (int mm = 1; mm < 16; mm <<= 1) t = fmaxf(t, __shfl_xor(t, mm, 64));
      float mn = fmaxf(m_run[j], t);
      corr[j] = exp2f((m_run[j] - mn) * SCL);
      float s = 0.f;
#pragma unroll
      for (int tt = 0; tt < 4; ++tt) {
        float p = exp2f((sc[tt][j] - mn) * SCL);
        sc[tt][j] = p;
        s += p;
      }
#pragma unroll
      for (int mm = 1; mm < 16; mm <<= 1) s += __shfl_xor(s, mm, 64);
      l_run[j] = l_run[j] * corr[j] + s;
      m_run[j] = mn;
    }
#pragma unroll
    for (int n = 0; n < 4; ++n)
#pragma unroll
      for (int j = 0; j < 4; ++j) o[n][j] *= corr[j];

    // P -> wave-private LDS (swizzled), then read back as A-fragments
    unsigned short* Pw = &Ps[wv][0];
#pragma unroll
    for (int tt = 0; tt < 4; ++tt) {
#pragma unroll
      for (int j = 0; j < 4; ++j) {
        int row = g * 4 + j;
        int col = tt * 16 + c16;
        int ch = (col >> 3) ^ (row & 7);
        Pw[row * 64 + ch * 8 + (col & 7)] = f2bf(sc[tt][j]);
      }
    }

#pragma unroll
    for (int cc = 0; cc < 2; ++cc) {
      s16x8 pf = *(const s16x8*)&Pw[c16 * 64 + ((cc * 4 + g) ^ (c16 & 7)) * 8];
#pragma unroll
      for (int n = 0; n < 4; ++n) {
        int vrow = n * 16 + c16;
        s16x8 vf = *(const s16x8*)&VTs[vrow * 64 + ((cc * 4 + g) ^ (vrow & 7)) * 8];
        o[n] = __builtin_amdgcn_mfma_f32_16x16x32_bf16(pf, vf, o[n], 0, 0, 0);
      }
    }
  }

#pragma unroll
  for (int n = 0; n < 4; ++n) {
#pragma unroll
    for (int j = 0; j < 4; ++j) {
      int row = q0 + wv * 16 + g * 4 + j;
      int col = h * 64 + n * 16 + c16;
      attn[(size_t)(b * 2048 + row) * 1024 + col] = f2bf(o[n][j] / l_run[j]);
    }
  }
}

extern "C" void kernel_launch(void* const* d_in, const int* in_sizes, int n_in,
                              void* d_out, int out_size, void* d_ws, size_t ws_size,
                              hipStream_t stream) {
  const float* x  = (const float*)d_in[0];
  const float* Wq = (const float*)d_in[1];
  const float* bq = (const float*)d_in[2];
  const float* Wk = (const float*)d_in[3];
  const float* bk = (const float*)d_in[4];
  const float* Wv = (const float*)d_in[5];
  const float* bv = (const float*)d_in[6];
  const float* Wo = (const float*)d_in[7];
  const float* bo = (const float*)d_in[8];
  float* out = (float*)d_out;

  char* ws = (char*)d_ws;
  const size_t MB = 1024 * 1024;
  // Aliased layout (~42 MiB):
  //   [0,8)    xb (live -> QKV gemm), then attn (written by flash)
  //   [8,10)   wob (live -> final gemm)
  //   [10,16)  wcat (live -> QKV gemm); [10,18) vt (written after)
  //   [18,42)  qkv
  //   [42,..)  bcat
  unsigned short* xb   = (unsigned short*)(ws + 0);
  unsigned short* attn = (unsigned short*)(ws + 0);
  unsigned short* wob  = (unsigned short*)(ws + 8 * MB);
  unsigned short* wcat = (unsigned short*)(ws + 10 * MB);
  unsigned short* vt   = (unsigned short*)(ws + 10 * MB);
  unsigned short* qkv  = (unsigned short*)(ws + 18 * MB);
  float* bcat          = (float*)(ws + 42 * MB);

  cvt_f32_bf16<<<4096, 256, 0, stream>>>(x, xb, 4 * 1024 * 1024);
  cvt_f32_bf16<<<1024, 256, 0, stream>>>(Wq, wcat, 1024 * 1024);
  cvt_f32_bf16<<<1024, 256, 0, stream>>>(Wk, wcat + 1024 * 1024, 1024 * 1024);
  cvt_f32_bf16<<<1024, 256, 0, stream>>>(Wv, wcat + 2 * 1024 * 1024, 1024 * 1024);
  cvt_f32_bf16<<<1024, 256, 0, stream>>>(Wo, wob, 1024 * 1024);
  concat3<<<12, 256, 0, stream>>>(bq, bk, bv, bcat);

  gemm_bt<unsigned short><<<dim3(24, 32), 256, 0, stream>>>(
      xb, wcat, qkv, 4096, 3072, 1024, bcat);

  transpose_v<<<dim3(32, 32), 256, 0, stream>>>(qkv, vt);

  flash_attn<<<dim3(32, 32), 256, 0, stream>>>(qkv, vt, attn);

  gemm_bt<float><<<dim3(8, 32), 256, 0, stream>>>(
      attn, wob, out, 4096, 1024, 1024, bo);
}

// Round 3
// 171.477 us; speedup vs baseline: 1.2365x; 1.2365x over previous
//
#include <hip/hip_runtime.h>
#include <hip/hip_bf16.h>
#include <type_traits>

// MHA: x[2,2048,1024] fp32; W*[1024,1024] fp32; out fp32.
// Pipeline: cvt->bf16, QKV gemm (bf16 mfma), V-transpose, flash attn, out gemm.

typedef __attribute__((ext_vector_type(4))) float f32x4;
typedef __attribute__((ext_vector_type(16))) float f32x16;
typedef __attribute__((ext_vector_type(8))) short s16x8;
typedef __attribute__((ext_vector_type(4))) unsigned int u32x4;

#define GLDS16(g, l)                                                       \
  __builtin_amdgcn_global_load_lds(                                        \
      (const __attribute__((address_space(1))) unsigned int*)(g),          \
      (__attribute__((address_space(3))) unsigned int*)(l), 16, 0, 0)

__device__ __forceinline__ unsigned short f2bf(float f) {
  unsigned int u = __builtin_bit_cast(unsigned int, f);
  u += 0x7fffu + ((u >> 16) & 1u);
  return (unsigned short)(u >> 16);
}

__device__ __forceinline__ unsigned int cvtpk_bf16(float lo, float hi) {
  unsigned int r;
  asm("v_cvt_pk_bf16_f32 %0, %1, %2" : "=v"(r) : "v"(lo), "v"(hi));
  return r;
}

__global__ void cvt_f32_bf16(const float* __restrict__ in,
                             unsigned short* __restrict__ out, int n) {
  int i = (blockIdx.x * blockDim.x + threadIdx.x) * 4;
  if (i < n) {
    float4 v = *reinterpret_cast<const float4*>(in + i);
    ushort4 o;
    o.x = f2bf(v.x); o.y = f2bf(v.y); o.z = f2bf(v.z); o.w = f2bf(v.w);
    *reinterpret_cast<ushort4*>(out + i) = o;
  }
}

__global__ void concat3(const float* __restrict__ a, const float* __restrict__ b,
                        const float* __restrict__ c, float* __restrict__ out) {
  int i = blockIdx.x * blockDim.x + threadIdx.x;  // 3072 threads
  const float* src = (i < 1024) ? a : ((i < 2048) ? b : c);
  out[i] = src[i & 1023];
}

// C[M,N] = A[M,K] * B[N,K]^T + bias ; A,B bf16 (ushort), C f32 or bf16.
// 128x128 tile, BK=32, 4 waves (2x2), 16x16x32 bf16 MFMA, global_load_lds.
template <typename CT>
__global__ __launch_bounds__(256, 2) void gemm_bt(
    const unsigned short* __restrict__ A, const unsigned short* __restrict__ B,
    CT* __restrict__ C, int M, int N, int K, const float* __restrict__ bias) {
  __shared__ unsigned short As[128 * 32];
  __shared__ unsigned short Bs[128 * 32];
  const int tid = threadIdx.x;
  const int wv = tid >> 6, lane = tid & 63;
  const int g = lane >> 4, c16 = lane & 15;
  const int wm = wv >> 1, wn = wv & 1;
  const int bm = blockIdx.y, bn = blockIdx.x;

  const unsigned short* Ab = A + (size_t)bm * 128 * K;
  const unsigned short* Bb = B + (size_t)bn * 128 * K;

  f32x4 acc[4][4] = {};

  for (int k0 = 0; k0 < K; k0 += 32) {
    __syncthreads();
#pragma unroll
    for (int r = 0; r < 2; ++r) {
      int i = r * 256 + tid;
      int row = i >> 2, col = (i & 3) * 8;
      GLDS16(Ab + (size_t)row * K + k0 + col, &As[i * 8]);
    }
#pragma unroll
    for (int r = 0; r < 2; ++r) {
      int i = r * 256 + tid;
      int row = i >> 2, col = (i & 3) * 8;
      GLDS16(Bb + (size_t)row * K + k0 + col, &Bs[i * 8]);
    }
    __syncthreads();

    s16x8 af[4], bfv[4];
#pragma unroll
    for (int m = 0; m < 4; ++m)
      af[m] = *(const s16x8*)&As[(wm * 64 + m * 16 + c16) * 32 + g * 8];
#pragma unroll
    for (int n = 0; n < 4; ++n)
      bfv[n] = *(const s16x8*)&Bs[(wn * 64 + n * 16 + c16) * 32 + g * 8];
#pragma unroll
    for (int m = 0; m < 4; ++m)
#pragma unroll
      for (int n = 0; n < 4; ++n)
        acc[m][n] = __builtin_amdgcn_mfma_f32_16x16x32_bf16(af[m], bfv[n],
                                                            acc[m][n], 0, 0, 0);
  }

#pragma unroll
  for (int m = 0; m < 4; ++m) {
#pragma unroll
    for (int n = 0; n < 4; ++n) {
      int col = bn * 128 + wn * 64 + n * 16 + c16;
      float bb = bias ? bias[col] : 0.f;
#pragma unroll
      for (int j = 0; j < 4; ++j) {
        int row = bm * 128 + wm * 64 + m * 16 + g * 4 + j;
        float v = acc[m][n][j] + bb;
        if constexpr (std::is_same<CT, float>::value)
          C[(size_t)row * N + col] = v;
        else
          C[(size_t)row * N + col] = f2bf(v);
      }
    }
  }
}

// vt[bh][64][2048] = transpose of V part of qkv (cols 2048..3071) per (b,h).
__global__ void transpose_v(const unsigned short* __restrict__ qkv,
                            unsigned short* __restrict__ vt) {
  __shared__ unsigned short T[64 * 80];
  const int tid = threadIdx.x;
  const int st = blockIdx.x, bh = blockIdx.y;
  const int b = bh >> 4, h = bh & 15;
  const int s0 = st * 64;

  int srow = tid >> 2, d0 = (tid & 3) * 16;
  const unsigned short* src =
      qkv + (size_t)(b * 2048 + s0 + srow) * 3072 + 2048 + h * 64 + d0;
  s16x8 v0 = *(const s16x8*)(src);
  s16x8 v1 = *(const s16x8*)(src + 8);
  *(s16x8*)&T[srow * 80 + d0] = v0;
  *(s16x8*)&T[srow * 80 + d0 + 8] = v1;
  __syncthreads();

  int drow = tid >> 2, sl = (tid & 3) * 16;
  s16x8 o0, o1;
#pragma unroll
  for (int j = 0; j < 8; ++j) o0[j] = (short)T[(sl + j) * 80 + drow];
#pragma unroll
  for (int j = 0; j < 8; ++j) o1[j] = (short)T[(sl + 8 + j) * 80 + drow];
  unsigned short* dst = vt + (size_t)(bh * 64 + drow) * 2048 + s0 + sl;
  *(s16x8*)dst = o0;
  *(s16x8*)(dst + 8) = o1;
}

// Flash attention, 8-warp 32x32 swapped-QK^T structure (T12):
// grid (8 qtiles, 32 bh), 512 thr = 8 waves; each wave owns 32 q-rows.
// KVBLK=64. K/VT staged double-buffered via global_load_lds (pre-swizzled
// source + XOR-swizzled reads). Softmax fully in-register: mfma(K,Q) puts
// the P-row (over keys) lane-local (q = lane&31 "P basis"); PV output o is
// in the MFMA D basis (q = (r&3)+8*(r>>2)+4*hi). corr and 1/l must be
// basis-transformed via variable-src __shfl before touching o.  (R2 bug.)
__global__ __launch_bounds__(512) void flash_attn(
    const unsigned short* __restrict__ qkv, const unsigned short* __restrict__ vt,
    unsigned short* __restrict__ attn) {
  __shared__ unsigned short Ks[2][64 * 64];
  __shared__ unsigned short VTs[2][64 * 64];

  const int tid = threadIdx.x;
  const int wv = tid >> 6, lane = tid & 63;
  const int col = lane & 31, hi = lane >> 5;
  const int qt = blockIdx.x, bh = blockIdx.y;
  const int b = bh >> 4, h = bh & 15;
  const int qrow0 = qt * 256 + wv * 32;

  // staging addresses (1 chunk of 16B per thread per tile)
  const int srow = tid >> 3;           // 0..63
  const int scs = tid & 7;
  const int sqc = scs ^ (srow & 7);    // pre-swizzled source chunk
  const unsigned short* kgsrc =
      qkv + (size_t)(b * 2048 + srow) * 3072 + 1024 + h * 64 + sqc * 8;
  const unsigned short* vgsrc = vt + (size_t)(bh * 64 + srow) * 2048 + sqc * 8;

  // Q B-fragments (col q = lane&31, k = hi*8+j), direct from global
  s16x8 qb[4];
#pragma unroll
  for (int ds = 0; ds < 4; ++ds)
    qb[ds] = *(const s16x8*)(qkv + (size_t)(b * 2048 + qrow0 + col) * 3072 +
                             h * 64 + ds * 16 + hi * 8);

  float m_run = -__builtin_inff(), l_run = 0.f;
  f32x16 o[2] = {};
  const float SCL = 0.125f * 1.44269504088896340736f;  // (1/sqrt(64))*log2(e)

  GLDS16(kgsrc, &Ks[0][tid * 8]);
  GLDS16(vgsrc, &VTs[0][tid * 8]);
  __syncthreads();

  for (int kt = 0; kt < 32; ++kt) {
    const int cur = kt & 1;
    if (kt < 31) {  // prefetch next tile into other buffer (overlaps compute)
      const size_t k0n = (size_t)(kt + 1) * 64;
      GLDS16(kgsrc + k0n * 3072, &Ks[cur ^ 1][tid * 8]);
      GLDS16(vgsrc + k0n, &VTs[cur ^ 1][tid * 8]);
    }

    // QK^T swapped: st[kb] = K(32 keys x 64d) * Q^T -> D[key][q]
    f32x16 st[2];
#pragma unroll
    for (int kb = 0; kb < 2; ++kb) {
      f32x16 a = {};
#pragma unroll
      for (int ds = 0; ds < 4; ++ds) {
        int row = kb * 32 + col;
        int cs = ds * 2 + hi;
        s16x8 ka = *(const s16x8*)&Ks[cur][row * 64 + (cs ^ (row & 7)) * 8];
        a = __builtin_amdgcn_mfma_f32_32x32x16_bf16(ka, qb[ds], a, 0, 0, 0);
      }
      st[kb] = a;
    }

    // online softmax, fully in-register (lane owns q=lane&31; 32 of 64 keys
    // in-lane, other 32 in lane^32)
    float t = st[0][0];
#pragma unroll
    for (int r = 1; r < 16; ++r) t = fmaxf(t, st[0][r]);
#pragma unroll
    for (int r = 0; r < 16; ++r) t = fmaxf(t, st[1][r]);
    t = fmaxf(t, __shfl_xor(t, 32, 64));
    const float mn = fmaxf(m_run, t);
    const float corr = exp2f((m_run - mn) * SCL);
    float s = 0.f;
#pragma unroll
    for (int kb = 0; kb < 2; ++kb)
#pragma unroll
      for (int r = 0; r < 16; ++r) {
        float p = exp2f((st[kb][r] - mn) * SCL);
        st[kb][r] = p;
        s += p;
      }
    s += __shfl_xor(s, 32, 64);
    l_run = l_run * corr + s;
    m_run = mn;

    // Basis transform: o[n][r] belongs to q_local=(r&3)+8*(r>>2)+4*hi, but
    // corr is held by lane q_local (replicated q_local+32). Fetch per r.
    float corrD[16];
#pragma unroll
    for (int r = 0; r < 16; ++r)
      corrD[r] = __shfl(corr, (r & 3) + 8 * (r >> 2) + 4 * hi, 64);
#pragma unroll
    for (int n = 0; n < 2; ++n)
#pragma unroll
      for (int r = 0; r < 16; ++r) o[n][r] *= corrD[r];

    // P -> A-fragments in-register (cvt_pk + permlane32_swap), then PV
#pragma unroll
    for (int kb = 0; kb < 2; ++kb) {
#pragma unroll
      for (int half = 0; half < 2; ++half) {
        const int p0 = half * 8;
        unsigned int a0 = cvtpk_bf16(st[kb][p0 + 0], st[kb][p0 + 1]);
        unsigned int b0 = cvtpk_bf16(st[kb][p0 + 4], st[kb][p0 + 5]);
        unsigned int a1 = cvtpk_bf16(st[kb][p0 + 2], st[kb][p0 + 3]);
        unsigned int b1 = cvtpk_bf16(st[kb][p0 + 6], st[kb][p0 + 7]);
        asm("v_permlane32_swap_b32 %0, %1" : "+v"(a0), "+v"(b0));
        asm("v_permlane32_swap_b32 %0, %1" : "+v"(a1), "+v"(b1));
        u32x4 pw;
        pw[0] = a0; pw[1] = a1; pw[2] = b0; pw[3] = b1;
        const s16x8 pa = __builtin_bit_cast(s16x8, pw);
        const int ks = kb * 2 + half;  // 16-key step
#pragma unroll
        for (int n = 0; n < 2; ++n) {
          int row = n * 32 + col;
          int cs = ks * 2 + hi;
          s16x8 vb = *(const s16x8*)&VTs[cur][row * 64 + (cs ^ (row & 7)) * 8];
          o[n] = __builtin_amdgcn_mfma_f32_32x32x16_bf16(pa, vb, o[n], 0, 0, 0);
        }
      }
    }
    __syncthreads();  // drains prefetch (implicit vmcnt(0)) + protects buffers
  }

  // Final normalize: 1/l is in the P basis; transform to D basis like corr.
  const float inv = 1.f / l_run;
  float invD[16];
#pragma unroll
  for (int r = 0; r < 16; ++r)
    invD[r] = __shfl(inv, (r & 3) + 8 * (r >> 2) + 4 * hi, 64);
#pragma unroll
  for (int n = 0; n < 2; ++n) {
#pragma unroll
    for (int r = 0; r < 16; ++r) {
      int q = qrow0 + (r & 3) + 8 * (r >> 2) + 4 * hi;
      int d = h * 64 + n * 32 + col;
      attn[(size_t)(b * 2048 + q) * 1024 + d] = f2bf(o[n][r] * invD[r]);
    }
  }
}

extern "C" void kernel_launch(void* const* d_in, const int* in_sizes, int n_in,
                              void* d_out, int out_size, void* d_ws, size_t ws_size,
                              hipStream_t stream) {
  const float* x  = (const float*)d_in[0];
  const float* Wq = (const float*)d_in[1];
  const float* bq = (const float*)d_in[2];
  const float* Wk = (const float*)d_in[3];
  const float* bk = (const float*)d_in[4];
  const float* Wv = (const float*)d_in[5];
  const float* bv = (const float*)d_in[6];
  const float* Wo = (const float*)d_in[7];
  const float* bo = (const float*)d_in[8];
  float* out = (float*)d_out;

  char* ws = (char*)d_ws;
  const size_t MB = 1024 * 1024;
  // Aliased layout (~42 MiB):
  //   [0,8)    xb (live -> QKV gemm), then attn (written by flash)
  //   [8,10)   wob (live -> final gemm)
  //   [10,16)  wcat (live -> QKV gemm); [10,18) vt (written after)
  //   [18,42)  qkv
  //   [42,..)  bcat
  unsigned short* xb   = (unsigned short*)(ws + 0);
  unsigned short* attn = (unsigned short*)(ws + 0);
  unsigned short* wob  = (unsigned short*)(ws + 8 * MB);
  unsigned short* wcat = (unsigned short*)(ws + 10 * MB);
  unsigned short* vt   = (unsigned short*)(ws + 10 * MB);
  unsigned short* qkv  = (unsigned short*)(ws + 18 * MB);
  float* bcat          = (float*)(ws + 42 * MB);

  cvt_f32_bf16<<<4096, 256, 0, stream>>>(x, xb, 4 * 1024 * 1024);
  cvt_f32_bf16<<<1024, 256, 0, stream>>>(Wq, wcat, 1024 * 1024);
  cvt_f32_bf16<<<1024, 256, 0, stream>>>(Wk, wcat + 1024 * 1024, 1024 * 1024);
  cvt_f32_bf16<<<1024, 256, 0, stream>>>(Wv, wcat + 2 * 1024 * 1024, 1024 * 1024);
  cvt_f32_bf16<<<1024, 256, 0, stream>>>(Wo, wob, 1024 * 1024);
  concat3<<<12, 256, 0, stream>>>(bq, bk, bv, bcat);

  gemm_bt<unsigned short><<<dim3(24, 32), 256, 0, stream>>>(
      xb, wcat, qkv, 4096, 3072, 1024, bcat);

  transpose_v<<<dim3(32, 32), 256, 0, stream>>>(qkv, vt);

  flash_attn<<<dim3(8, 32), 512, 0, stream>>>(qkv, vt, attn);

  gemm_bt<float><<<dim3(8, 32), 256, 0, stream>>>(
      attn, wob, out, 4096, 1024, 1024, bo);
}

// Round 4
// 153.729 us; speedup vs baseline: 1.3793x; 1.1155x over previous
//
#include <hip/hip_runtime.h>
#include <hip/hip_bf16.h>
#include <type_traits>

// MHA: x[2,2048,1024] fp32; W*[1024,1024] fp32; out fp32.
// Pipeline: cvt->bf16, QKV gemm (bf16 mfma), V-transpose, flash attn, out gemm.

typedef __attribute__((ext_vector_type(4))) float f32x4;
typedef __attribute__((ext_vector_type(16))) float f32x16;
typedef __attribute__((ext_vector_type(8))) short s16x8;
typedef __attribute__((ext_vector_type(4))) unsigned int u32x4;

#define GLDS16(g, l)                                                       \
  __builtin_amdgcn_global_load_lds(                                        \
      (const __attribute__((address_space(1))) unsigned int*)(g),          \
      (__attribute__((address_space(3))) unsigned int*)(l), 16, 0, 0)

__device__ __forceinline__ unsigned short f2bf(float f) {
  unsigned int u = __builtin_bit_cast(unsigned int, f);
  u += 0x7fffu + ((u >> 16) & 1u);
  return (unsigned short)(u >> 16);
}

__device__ __forceinline__ unsigned int cvtpk_bf16(float lo, float hi) {
  unsigned int r;
  asm("v_cvt_pk_bf16_f32 %0, %1, %2" : "=v"(r) : "v"(lo), "v"(hi));
  return r;
}

__global__ void cvt_f32_bf16(const float* __restrict__ in,
                             unsigned short* __restrict__ out, int n) {
  int i = (blockIdx.x * blockDim.x + threadIdx.x) * 4;
  if (i < n) {
    float4 v = *reinterpret_cast<const float4*>(in + i);
    ushort4 o;
    o.x = f2bf(v.x); o.y = f2bf(v.y); o.z = f2bf(v.z); o.w = f2bf(v.w);
    *reinterpret_cast<ushort4*>(out + i) = o;
  }
}

__global__ void concat3(const float* __restrict__ a, const float* __restrict__ b,
                        const float* __restrict__ c, float* __restrict__ out) {
  int i = blockIdx.x * blockDim.x + threadIdx.x;  // 3072 threads
  const float* src = (i < 1024) ? a : ((i < 2048) ? b : c);
  out[i] = src[i & 1023];
}

// C[M,N] = A[M,K] * B[N,K]^T + bias ; A,B bf16 (ushort), C f32 or bf16.
// 128x128 tile, BK=32, 4 waves (2x2), 16x16x32 bf16 MFMA, global_load_lds.
template <typename CT>
__global__ __launch_bounds__(256, 2) void gemm_bt(
    const unsigned short* __restrict__ A, const unsigned short* __restrict__ B,
    CT* __restrict__ C, int M, int N, int K, const float* __restrict__ bias) {
  __shared__ unsigned short As[128 * 32];
  __shared__ unsigned short Bs[128 * 32];
  const int tid = threadIdx.x;
  const int wv = tid >> 6, lane = tid & 63;
  const int g = lane >> 4, c16 = lane & 15;
  const int wm = wv >> 1, wn = wv & 1;
  const int bm = blockIdx.y, bn = blockIdx.x;

  const unsigned short* Ab = A + (size_t)bm * 128 * K;
  const unsigned short* Bb = B + (size_t)bn * 128 * K;

  f32x4 acc[4][4] = {};

  for (int k0 = 0; k0 < K; k0 += 32) {
    __syncthreads();
#pragma unroll
    for (int r = 0; r < 2; ++r) {
      int i = r * 256 + tid;
      int row = i >> 2, col = (i & 3) * 8;
      GLDS16(Ab + (size_t)row * K + k0 + col, &As[i * 8]);
    }
#pragma unroll
    for (int r = 0; r < 2; ++r) {
      int i = r * 256 + tid;
      int row = i >> 2, col = (i & 3) * 8;
      GLDS16(Bb + (size_t)row * K + k0 + col, &Bs[i * 8]);
    }
    __syncthreads();

    s16x8 af[4], bfv[4];
#pragma unroll
    for (int m = 0; m < 4; ++m)
      af[m] = *(const s16x8*)&As[(wm * 64 + m * 16 + c16) * 32 + g * 8];
#pragma unroll
    for (int n = 0; n < 4; ++n)
      bfv[n] = *(const s16x8*)&Bs[(wn * 64 + n * 16 + c16) * 32 + g * 8];
#pragma unroll
    for (int m = 0; m < 4; ++m)
#pragma unroll
      for (int n = 0; n < 4; ++n)
        acc[m][n] = __builtin_amdgcn_mfma_f32_16x16x32_bf16(af[m], bfv[n],
                                                            acc[m][n], 0, 0, 0);
  }

#pragma unroll
  for (int m = 0; m < 4; ++m) {
#pragma unroll
    for (int n = 0; n < 4; ++n) {
      int col = bn * 128 + wn * 64 + n * 16 + c16;
      float bb = bias ? bias[col] : 0.f;
#pragma unroll
      for (int j = 0; j < 4; ++j) {
        int row = bm * 128 + wm * 64 + m * 16 + g * 4 + j;
        float v = acc[m][n][j] + bb;
        if constexpr (std::is_same<CT, float>::value)
          C[(size_t)row * N + col] = v;
        else
          C[(size_t)row * N + col] = f2bf(v);
      }
    }
  }
}

// vt[bh][64][2048] = transpose of V part of qkv (cols 2048..3071) per (b,h).
__global__ void transpose_v(const unsigned short* __restrict__ qkv,
                            unsigned short* __restrict__ vt) {
  __shared__ unsigned short T[64 * 80];
  const int tid = threadIdx.x;
  const int st = blockIdx.x, bh = blockIdx.y;
  const int b = bh >> 4, h = bh & 15;
  const int s0 = st * 64;

  int srow = tid >> 2, d0 = (tid & 3) * 16;
  const unsigned short* src =
      qkv + (size_t)(b * 2048 + s0 + srow) * 3072 + 2048 + h * 64 + d0;
  s16x8 v0 = *(const s16x8*)(src);
  s16x8 v1 = *(const s16x8*)(src + 8);
  *(s16x8*)&T[srow * 80 + d0] = v0;
  *(s16x8*)&T[srow * 80 + d0 + 8] = v1;
  __syncthreads();

  int drow = tid >> 2, sl = (tid & 3) * 16;
  s16x8 o0, o1;
#pragma unroll
  for (int j = 0; j < 8; ++j) o0[j] = (short)T[(sl + j) * 80 + drow];
#pragma unroll
  for (int j = 0; j < 8; ++j) o1[j] = (short)T[(sl + 8 + j) * 80 + drow];
  unsigned short* dst = vt + (size_t)(bh * 64 + drow) * 2048 + s0 + sl;
  *(s16x8*)dst = o0;
  *(s16x8*)(dst + 8) = o1;
}

// Flash attention, split-KV 16-wave blocks.
// grid (8 qtiles, 32 bh), 1024 thr = 16 waves. Waves 0-7 ("half 0") process
// keys [0,1024), waves 8-15 keys [1024,2048), same 256 q-rows; merged via LDS.
// Swapped QK^T (mfma(K,Q)) keeps the P-row lane-local (q = lane&31 "P basis");
// PV output o is in the MFMA D basis (q = (r&3)+8*(r>>2)+4*hi): corr / 1/l
// must be basis-transformed via variable-src __shfl before touching o.
// Defer-max (T13): skip the o-rescale unless the tile max grew > 8/SCL.
__global__ __launch_bounds__(1024) void flash_attn(
    const unsigned short* __restrict__ qkv, const unsigned short* __restrict__ vt,
    unsigned short* __restrict__ attn) {
  __shared__ unsigned short Ks[2][2][64 * 64];
  __shared__ unsigned short VTs[2][2][64 * 64];
  __shared__ float Mo[8][32][65];
  __shared__ float Mm[8][32];
  __shared__ float Ml[8][32];

  const int tid = threadIdx.x;
  const int wv = tid >> 6, lane = tid & 63;
  const int half = wv >> 3, w8 = wv & 7;
  const int col = lane & 31, hi = lane >> 5;
  const int qt = blockIdx.x, bh = blockIdx.y;
  const int b = bh >> 4, h = bh & 15;
  const int qrow0 = qt * 256 + w8 * 32;

  // staging addresses: 512 threads per half stage that half's 64x64 K,V tiles
  const int stid = tid & 511;
  const int srow = stid >> 3;          // 0..63
  const int scs = stid & 7;
  const int sqc = scs ^ (srow & 7);    // pre-swizzled source chunk
  const int kbase = half * 1024;       // this half's key offset
  const unsigned short* kgsrc =
      qkv + (size_t)(b * 2048 + kbase + srow) * 3072 + 1024 + h * 64 + sqc * 8;
  const unsigned short* vgsrc =
      vt + (size_t)(bh * 64 + srow) * 2048 + kbase + sqc * 8;

  // Q B-fragments (col q = lane&31, k = hi*8+j), direct from global
  s16x8 qb[4];
#pragma unroll
  for (int ds = 0; ds < 4; ++ds)
    qb[ds] = *(const s16x8*)(qkv + (size_t)(b * 2048 + qrow0 + col) * 3072 +
                             h * 64 + ds * 16 + hi * 8);

  float m_run = -__builtin_inff(), l_run = 0.f;
  f32x16 o[2] = {};
  const float SCL = 0.125f * 1.44269504088896340736f;  // (1/sqrt(64))*log2(e)
  const float THR_RAW = 8.0f / SCL;                    // defer-max threshold

  GLDS16(kgsrc, &Ks[half][0][stid * 8]);
  GLDS16(vgsrc, &VTs[half][0][stid * 8]);
  __syncthreads();

  for (int kt = 0; kt < 16; ++kt) {
    const int cur = kt & 1;
    if (kt < 15) {  // prefetch next tile into other buffer (overlaps compute)
      GLDS16(kgsrc + (size_t)(kt + 1) * 64 * 3072, &Ks[half][cur ^ 1][stid * 8]);
      GLDS16(vgsrc + (kt + 1) * 64, &VTs[half][cur ^ 1][stid * 8]);
    }

    // QK^T swapped: st[kb] = K(32 keys x 64d) * Q^T -> D[key][q]
    f32x16 st[2];
    __builtin_amdgcn_s_setprio(1);
#pragma unroll
    for (int kb = 0; kb < 2; ++kb) {
      f32x16 a = {};
#pragma unroll
      for (int ds = 0; ds < 4; ++ds) {
        int row = kb * 32 + col;
        int cs = ds * 2 + hi;
        s16x8 ka = *(const s16x8*)&Ks[half][cur][row * 64 + (cs ^ (row & 7)) * 8];
        a = __builtin_amdgcn_mfma_f32_32x32x16_bf16(ka, qb[ds], a, 0, 0, 0);
      }
      st[kb] = a;
    }
    __builtin_amdgcn_s_setprio(0);

    // tree max over this lane's 32 score entries, then pair-lane combine
    float mx[8];
#pragma unroll
    for (int r = 0; r < 8; ++r)
      mx[r] = fmaxf(fmaxf(st[0][r], st[0][r + 8]),
                    fmaxf(st[1][r], st[1][r + 8]));
#pragma unroll
    for (int r = 0; r < 4; ++r) mx[r] = fmaxf(mx[r], mx[r + 4]);
    float t = fmaxf(fmaxf(mx[0], mx[1]), fmaxf(mx[2], mx[3]));
    t = fmaxf(t, __shfl_xor(t, 32, 64));

    // defer-max: only rescale when the max grew materially (rare)
    if (__any((t - m_run) > THR_RAW)) {
      const float mn = fmaxf(m_run, t);
      const float corr = exp2f((m_run - mn) * SCL);
      l_run *= corr;
      m_run = mn;
#pragma unroll
      for (int r = 0; r < 16; ++r) {
        float c = __shfl(corr, (r & 3) + 8 * (r >> 2) + 4 * hi, 64);
        o[0][r] *= c;
        o[1][r] *= c;
      }
    }

    // P = exp2((S - m)*SCL), partial sums with 4 accumulators
    float sm0 = 0.f, sm1 = 0.f, sm2 = 0.f, sm3 = 0.f;
#pragma unroll
    for (int kb = 0; kb < 2; ++kb)
#pragma unroll
      for (int r = 0; r < 16; ++r) {
        float p = exp2f((st[kb][r] - m_run) * SCL);
        st[kb][r] = p;
        if ((r & 3) == 0) sm0 += p;
        else if ((r & 3) == 1) sm1 += p;
        else if ((r & 3) == 2) sm2 += p;
        else sm3 += p;
      }
    float s = (sm0 + sm1) + (sm2 + sm3);
    s += __shfl_xor(s, 32, 64);
    l_run += s;

    // P -> A-fragments in-register (cvt_pk + permlane32_swap), then PV
#pragma unroll
    for (int kb = 0; kb < 2; ++kb) {
#pragma unroll
      for (int hf = 0; hf < 2; ++hf) {
        const int p0 = hf * 8;
        unsigned int a0 = cvtpk_bf16(st[kb][p0 + 0], st[kb][p0 + 1]);
        unsigned int b0 = cvtpk_bf16(st[kb][p0 + 4], st[kb][p0 + 5]);
        unsigned int a1 = cvtpk_bf16(st[kb][p0 + 2], st[kb][p0 + 3]);
        unsigned int b1 = cvtpk_bf16(st[kb][p0 + 6], st[kb][p0 + 7]);
        asm("v_permlane32_swap_b32 %0, %1" : "+v"(a0), "+v"(b0));
        asm("v_permlane32_swap_b32 %0, %1" : "+v"(a1), "+v"(b1));
        u32x4 pw;
        pw[0] = a0; pw[1] = a1; pw[2] = b0; pw[3] = b1;
        const s16x8 pa = __builtin_bit_cast(s16x8, pw);
        const int ks = kb * 2 + hf;  // 16-key step
        __builtin_amdgcn_s_setprio(1);
#pragma unroll
        for (int n = 0; n < 2; ++n) {
          int row = n * 32 + col;
          int cs = ks * 2 + hi;
          s16x8 vb =
              *(const s16x8*)&VTs[half][cur][row * 64 + (cs ^ (row & 7)) * 8];
          o[n] = __builtin_amdgcn_mfma_f32_32x32x16_bf16(pa, vb, o[n], 0, 0, 0);
        }
        __builtin_amdgcn_s_setprio(0);
      }
    }
    __syncthreads();  // drains prefetch (implicit vmcnt(0)) + protects buffers
  }

  // -------- split-KV merge --------
  if (half == 1) {
#pragma unroll
    for (int r = 0; r < 16; ++r) {
      int qd = (r & 3) + 8 * (r >> 2) + 4 * hi;
      Mo[w8][qd][col] = o[0][r];
      Mo[w8][qd][32 + col] = o[1][r];
    }
    if (hi == 0) {
      Mm[w8][col] = m_run;
      Ml[w8][col] = l_run;
    }
  }
  __syncthreads();
  if (half == 0) {
    const float m1 = Mm[w8][col], l1 = Ml[w8][col];
    const float M = fmaxf(m_run, m1);
    const float c0 = exp2f((m_run - M) * SCL);
    const float c1 = exp2f((m1 - M) * SCL);
    const float linv = 1.f / (l_run * c0 + l1 * c1);
    const float f0 = c0 * linv, f1 = c1 * linv;
#pragma unroll
    for (int r = 0; r < 16; ++r) {
      int qd = (r & 3) + 8 * (r >> 2) + 4 * hi;
      float f0d = __shfl(f0, qd, 64);
      float f1d = __shfl(f1, qd, 64);
      float v0 = o[0][r] * f0d + Mo[w8][qd][col] * f1d;
      float v1 = o[1][r] * f0d + Mo[w8][qd][32 + col] * f1d;
      size_t base = (size_t)(b * 2048 + qrow0 + qd) * 1024 + h * 64;
      attn[base + col] = f2bf(v0);
      attn[base + 32 + col] = f2bf(v1);
    }
  }
}

extern "C" void kernel_launch(void* const* d_in, const int* in_sizes, int n_in,
                              void* d_out, int out_size, void* d_ws, size_t ws_size,
                              hipStream_t stream) {
  const float* x  = (const float*)d_in[0];
  const float* Wq = (const float*)d_in[1];
  const float* bq = (const float*)d_in[2];
  const float* Wk = (const float*)d_in[3];
  const float* bk = (const float*)d_in[4];
  const float* Wv = (const float*)d_in[5];
  const float* bv = (const float*)d_in[6];
  const float* Wo = (const float*)d_in[7];
  const float* bo = (const float*)d_in[8];
  float* out = (float*)d_out;

  char* ws = (char*)d_ws;
  const size_t MB = 1024 * 1024;
  // Aliased layout (~42 MiB):
  //   [0,8)    xb (live -> QKV gemm), then attn (written by flash)
  //   [8,10)   wob (live -> final gemm)
  //   [10,16)  wcat (live -> QKV gemm); [10,18) vt (written after)
  //   [18,42)  qkv
  //   [42,..)  bcat
  unsigned short* xb   = (unsigned short*)(ws + 0);
  unsigned short* attn = (unsigned short*)(ws + 0);
  unsigned short* wob  = (unsigned short*)(ws + 8 * MB);
  unsigned short* wcat = (unsigned short*)(ws + 10 * MB);
  unsigned short* vt   = (unsigned short*)(ws + 10 * MB);
  unsigned short* qkv  = (unsigned short*)(ws + 18 * MB);
  float* bcat          = (float*)(ws + 42 * MB);

  cvt_f32_bf16<<<4096, 256, 0, stream>>>(x, xb, 4 * 1024 * 1024);
  cvt_f32_bf16<<<1024, 256, 0, stream>>>(Wq, wcat, 1024 * 1024);
  cvt_f32_bf16<<<1024, 256, 0, stream>>>(Wk, wcat + 1024 * 1024, 1024 * 1024);
  cvt_f32_bf16<<<1024, 256, 0, stream>>>(Wv, wcat + 2 * 1024 * 1024, 1024 * 1024);
  cvt_f32_bf16<<<1024, 256, 0, stream>>>(Wo, wob, 1024 * 1024);
  concat3<<<12, 256, 0, stream>>>(bq, bk, bv, bcat);

  gemm_bt<unsigned short><<<dim3(24, 32), 256, 0, stream>>>(
      xb, wcat, qkv, 4096, 3072, 1024, bcat);

  transpose_v<<<dim3(32, 32), 256, 0, stream>>>(qkv, vt);

  flash_attn<<<dim3(8, 32), 1024, 0, stream>>>(qkv, vt, attn);

  gemm_bt<float><<<dim3(8, 32), 256, 0, stream>>>(
      attn, wob, out, 4096, 1024, 1024, bo);
}